// Round 1
// baseline (413.537 us; speedup 1.0000x reference)
//
#include <hip/hip_runtime.h>
#include <cmath>

#define B_   128
#define H_   256
#define W_   256
#define WC_  129
#define L_   182
#define NF   256
#define LOG2N 8

// 256-point in-place radix-2 DIT FFT. Data must be pre-loaded into LDS in
// bit-reversed order. 128 threads, one butterfly per thread per stage.
__device__ __forceinline__ void fft256(float* re, float* im, int t) {
  #pragma unroll
  for (int s = 0; s < LOG2N; ++s) {
    int m   = 1 << s;
    int pos = t & (m - 1);
    int i0  = ((t >> s) << (s + 1)) + pos;
    int i1  = i0 + m;
    float ang = -3.14159265358979f * (float)pos / (float)m; // -2*pi*pos/(2m)
    float sw, cw;
    __sincosf(ang, &sw, &cw);
    float xr = re[i1], xi = im[i1];
    float tr = cw * xr - sw * xi;
    float ti = cw * xi + sw * xr;
    float ur = re[i0], ui = im[i0];
    re[i1] = ur - tr; im[i1] = ui - ti;
    re[i0] = ur + tr; im[i0] = ui + ti;
    __syncthreads();
  }
}

// One block per (b,row): luma + rfft along W. Store k=0..128 transposed as
// [b][k][row] so the column FFT pass reads contiguous memory.
__global__ __launch_bounds__(128) void row_fft_kernel(
    const float* __restrict__ data, float2* __restrict__ out) {
  __shared__ float re[NF], im[NF];
  int bid = blockIdx.x;
  int b   = bid >> 8;      // / 256
  int row = bid & 255;
  int t   = threadIdx.x;   // 0..127
  const float* p0 = data + ((size_t)b * 3) * (H_ * W_) + (size_t)row * W_;
  #pragma unroll
  for (int e = 0; e < 2; ++e) {
    int i = t + e * 128;
    float r  = p0[i];
    float g  = p0[H_ * W_ + i];
    float bl = p0[2 * H_ * W_ + i];
    float gray = 0.299f * r + 0.587f * g + 0.114f * bl;
    int rv = (int)(__brev((unsigned)i) >> 24);  // 8-bit bit reversal
    re[rv] = gray;
    im[rv] = 0.f;
  }
  __syncthreads();
  fft256(re, im, t);
  size_t base = ((size_t)b * WC_) * H_ + row;
  out[base + (size_t)t * H_] = make_float2(re[t], im[t]);
  if (t == 0)
    out[base + (size_t)128 * H_] = make_float2(re[128], im[128]);
}

// One block per (b,k): 256-point complex FFT down the rows, then log-power
// and atomic accumulation into per-batch radial bins.
__global__ __launch_bounds__(128) void col_fft_kernel(
    const float2* __restrict__ in, const int* __restrict__ radius,
    float* __restrict__ bins) {
  __shared__ float re[NF], im[NF];
  int bid = blockIdx.x;
  int b   = bid / WC_;
  int k   = bid - b * WC_;
  int t   = threadIdx.x;
  const float2* p = in + ((size_t)b * WC_ + k) * H_;
  #pragma unroll
  for (int e = 0; e < 2; ++e) {
    int i = t + e * 128;
    float2 v = p[i];
    int rv = (int)(__brev((unsigned)i) >> 24);
    re[rv] = v.x;
    im[rv] = v.y;
  }
  __syncthreads();
  fft256(re, im, t);
  float* bb = bins + (size_t)b * L_;
  #pragma unroll
  for (int e = 0; e < 2; ++e) {
    int r  = t + e * 128;
    float pw  = re[r] * re[r] + im[r] * im[r];
    float val = 20.f * logf(pw + 1e-8f);
    atomicAdd(&bb[radius[r * WC_ + k]], val);
  }
}

// Radial bin counts (same for every batch sample).
__global__ __launch_bounds__(256) void count_kernel(
    const int* __restrict__ radius, float* __restrict__ counts) {
  __shared__ float c[L_];
  int t = threadIdx.x;
  for (int i = t; i < L_; i += 256) c[i] = 0.f;
  __syncthreads();
  for (int i = t; i < H_ * WC_; i += 256) atomicAdd(&c[radius[i]], 1.0f);
  __syncthreads();
  for (int i = t; i < L_; i += 256) counts[i] = c[i];
}

// One block per batch sample: segment mean, min-max normalize, L1 vs mean.
__global__ __launch_bounds__(256) void loss_kernel(
    const float* __restrict__ bins, const float* __restrict__ counts,
    const float* __restrict__ mean, float* __restrict__ out) {
  int b = blockIdx.x;
  int t = threadIdx.x;
  __shared__ float prof[L_];
  __shared__ float red[256];
  if (t < L_) prof[t] = bins[(size_t)b * L_ + t] / counts[t];
  __syncthreads();
  // min
  red[t] = (t < L_) ? prof[t] : INFINITY;
  __syncthreads();
  for (int s = 128; s > 0; s >>= 1) {
    if (t < s) red[t] = fminf(red[t], red[t + s]);
    __syncthreads();
  }
  float mn = red[0];
  __syncthreads();
  // max of (prof - min)
  red[t] = (t < L_) ? (prof[t] - mn) : -INFINITY;
  __syncthreads();
  for (int s = 128; s > 0; s >>= 1) {
    if (t < s) red[t] = fmaxf(red[t], red[t + s]);
    __syncthreads();
  }
  float mx = red[0];
  __syncthreads();
  // L1 sum
  red[t] = (t < L_) ? fabsf((prof[t] - mn) / mx - mean[t]) : 0.f;
  __syncthreads();
  for (int s = 128; s > 0; s >>= 1) {
    if (t < s) red[t] += red[t + s];
    __syncthreads();
  }
  if (t == 0) atomicAdd(out, red[0]);
}

extern "C" void kernel_launch(void* const* d_in, const int* in_sizes, int n_in,
                              void* d_out, int out_size, void* d_ws, size_t ws_size,
                              hipStream_t stream) {
  const float* data   = (const float*)d_in[0];  // [128,3,256,256] f32
  const float* mean   = (const float*)d_in[1];  // [182] f32
  const int*   radius = (const int*)d_in[2];    // [256,129] i32
  float* out = (float*)d_out;                   // scalar f32

  float2* stage1 = (float2*)d_ws;               // [B][WC][H] complex
  size_t stage1_bytes = (size_t)B_ * WC_ * H_ * sizeof(float2);
  float* bins   = (float*)((char*)d_ws + stage1_bytes);  // [B][L]
  float* counts = bins + (size_t)B_ * L_;                // [L]

  hipMemsetAsync(bins, 0, (size_t)B_ * L_ * sizeof(float), stream);
  hipMemsetAsync(out, 0, sizeof(float), stream);

  count_kernel<<<1, 256, 0, stream>>>(radius, counts);
  row_fft_kernel<<<B_ * H_, 128, 0, stream>>>(data, stage1);
  col_fft_kernel<<<B_ * WC_, 128, 0, stream>>>(stage1, radius, bins);
  loss_kernel<<<B_, 256, 0, stream>>>(bins, counts, mean, out);
}

// Round 2
// 200.245 us; speedup vs baseline: 2.0652x; 2.0652x over previous
//
#include <hip/hip_runtime.h>
#include <cmath>

#define B_   128
#define H_   256
#define W_   256
#define WC_  129
#define L_   182
#define PI_F 3.14159265358979f

// ---------------------------------------------------------------------------
// Wave-synchronous 256-point DIF FFT across one 64-lane wave.
// Lane l holds 4 complex elements in registers: slot j = x[l + 64*j].
// Stages N=256 and N=128 pair elements 128 and 64 apart -> purely in-lane.
// Remaining 6 stages are 64-pt FFTs across lanes via __shfl_xor (no LDS,
// no barriers). Output: storage index q = l + 64*j holds X[bitrev8(q)],
// i.e. lane l slot j holds X[4*bitrev6(l) + bitrev2(j)].
// ---------------------------------------------------------------------------
__device__ __forceinline__ void fft256_wave(float vr[4], float vi[4], int l) {
  float c0, s0;
  __sincosf(-2.f * PI_F * (float)l / 256.f, &s0, &c0);  // w0 = W256^l
  // stage N=256: (slot0,slot2) w=w0 ; (slot1,slot3) w=w0*(-i)=(s0,-c0)
  {
    float ur = vr[0] + vr[2], ui = vi[0] + vi[2];
    float dr = vr[0] - vr[2], di = vi[0] - vi[2];
    vr[0] = ur; vi[0] = ui;
    vr[2] = dr * c0 - di * s0; vi[2] = dr * s0 + di * c0;
    float c1 = s0, s1 = -c0;
    ur = vr[1] + vr[3]; ui = vi[1] + vi[3];
    dr = vr[1] - vr[3]; di = vi[1] - vi[3];
    vr[1] = ur; vi[1] = ui;
    vr[3] = dr * c1 - di * s1; vi[3] = dr * s1 + di * c1;
  }
  // stage N=128 (both halves): w = W128^l = w0^2
  {
    float c2 = c0 * c0 - s0 * s0, s2 = 2.f * c0 * s0;
    float ur = vr[0] + vr[1], ui = vi[0] + vi[1];
    float dr = vr[0] - vr[1], di = vi[0] - vi[1];
    vr[0] = ur; vi[0] = ui;
    vr[1] = dr * c2 - di * s2; vi[1] = dr * s2 + di * c2;
    ur = vr[2] + vr[3]; ui = vi[2] + vi[3];
    dr = vr[2] - vr[3]; di = vi[2] - vi[3];
    vr[2] = ur; vi[2] = ui;
    vr[3] = dr * c2 - di * s2; vi[3] = dr * s2 + di * c2;
  }
  // 6 cross-lane stages: 4 independent 64-pt FFTs (one per slot), shared
  // twiddles. lower lane: a+b ; upper lane: (b-a)*w, w=exp(-i*pi*(l&(h-1))/h)
  #pragma unroll
  for (int h = 32; h >= 1; h >>= 1) {
    int i = l & (h - 1);
    float c, s;
    __sincosf(-PI_F * (float)i / (float)h, &s, &c);
    bool up = (l & h) != 0;
    float cc = up ? c : 1.f;
    float ss = up ? s : 0.f;
    float sgn = up ? -1.f : 1.f;
    #pragma unroll
    for (int j = 0; j < 4; ++j) {
      float br = __shfl_xor(vr[j], h, 64);
      float bi = __shfl_xor(vi[j], h, 64);
      float tr = fmaf(sgn, vr[j], br);
      float ti = fmaf(sgn, vi[j], bi);
      vr[j] = tr * cc - ti * ss;
      vi[j] = tr * ss + ti * cc;
    }
  }
}

#define P1_ROWS 16
#define P1_STRIDE 259  // float2 stride; 259*2 mod 32 = 6 -> 16 distinct banks on bitrev read

// Pass 1: luma + row FFT. Block = 1024 thr = 16 waves = 16 rows of one image.
// Register FFT, then LDS transpose so the [b][k][row] intermediate is written
// with 16-row contiguous runs per k.
__global__ __launch_bounds__(1024) void pass1_kernel(
    const float* __restrict__ data, float2* __restrict__ inter) {
  __shared__ float2 tile[P1_ROWS * P1_STRIDE];
  int tid = threadIdx.x;
  int w = tid >> 6, l = tid & 63;
  int b = blockIdx.x >> 4;
  int row0 = (blockIdx.x & 15) * P1_ROWS;
  int row = row0 + w;
  const float* p0 = data + ((size_t)b * 3) * (H_ * W_) + (size_t)row * W_;
  float vr[4], vi[4];
  #pragma unroll
  for (int j = 0; j < 4; ++j) {
    int i = l + 64 * j;
    float r = p0[i], g = p0[H_ * W_ + i], bl = p0[2 * H_ * W_ + i];
    vr[j] = fmaf(0.299f, r, fmaf(0.587f, g, 0.114f * bl));
    vi[j] = 0.f;
  }
  fft256_wave(vr, vi, l);
  #pragma unroll
  for (int j = 0; j < 4; ++j)
    tile[w * P1_STRIDE + l + 64 * j] = make_float2(vr[j], vi[j]);
  __syncthreads();
  // out[(b*WC+k)*H + row0 + r] = X_row(k) ; X(k) sits at storage q=bitrev8(k)
  for (int f = tid; f < WC_ * P1_ROWS; f += 1024) {
    int k = f >> 4;
    int r = f & 15;
    int q = (int)(__brev((unsigned)k) >> 24);
    inter[((size_t)b * WC_ + k) * H_ + row0 + r] = tile[r * P1_STRIDE + q];
  }
}

// Pass 2: column FFT + log-power + radial binning. Block = 256 thr = 4 waves,
// each wave one column k of one image. LDS bins, one global atomic flush.
__global__ __launch_bounds__(256) void pass2_kernel(
    const float2* __restrict__ inter, const int* __restrict__ radius,
    float* __restrict__ bins) {
  __shared__ float lbins[L_];
  int tid = threadIdx.x;
  int wv = tid >> 6, l = tid & 63;
  int b = blockIdx.x / 33;
  int g = blockIdx.x - b * 33;
  int k = g * 4 + wv;
  for (int i = tid; i < L_; i += 256) lbins[i] = 0.f;
  __syncthreads();
  if (k < WC_) {
    const float2* p = inter + ((size_t)b * WC_ + k) * H_;
    float vr[4], vi[4];
    #pragma unroll
    for (int j = 0; j < 4; ++j) {
      float2 v = p[l + 64 * j];
      vr[j] = v.x; vi[j] = v.y;
    }
    fft256_wave(vr, vi, l);
    int rb = 4 * (int)(__brev((unsigned)l) >> 26);
    #pragma unroll
    for (int j = 0; j < 4; ++j) {
      int rf = rb + ((j == 1) ? 2 : (j == 2) ? 1 : j);  // bitrev2(j): 0,2,1,3
      float pw = vr[j] * vr[j] + vi[j] * vi[j];
      float val = 20.f * __logf(pw + 1e-8f);
      atomicAdd(&lbins[radius[rf * WC_ + k]], val);
    }
  }
  __syncthreads();
  float* bb = bins + (size_t)b * L_;
  for (int i = tid; i < L_; i += 256) atomicAdd(&bb[i], lbins[i]);
}

// Radial bin counts (batch-independent), 64 blocks.
__global__ __launch_bounds__(256) void count_kernel(
    const int* __restrict__ radius, float* __restrict__ counts) {
  __shared__ float c[L_];
  int t = threadIdx.x;
  for (int i = t; i < L_; i += 256) c[i] = 0.f;
  __syncthreads();
  for (int i = blockIdx.x * 256 + t; i < H_ * WC_; i += gridDim.x * 256)
    atomicAdd(&c[radius[i]], 1.f);
  __syncthreads();
  for (int i = t; i < L_; i += 256) atomicAdd(&counts[i], c[i]);
}

// One block per batch sample: segment mean, min-max normalize, L1 vs mean.
__global__ __launch_bounds__(256) void loss_kernel(
    const float* __restrict__ bins, const float* __restrict__ counts,
    const float* __restrict__ mean, float* __restrict__ out) {
  int b = blockIdx.x;
  int t = threadIdx.x;
  __shared__ float prof[L_];
  __shared__ float red[256];
  if (t < L_) prof[t] = bins[(size_t)b * L_ + t] / counts[t];
  __syncthreads();
  red[t] = (t < L_) ? prof[t] : INFINITY;
  __syncthreads();
  for (int s = 128; s > 0; s >>= 1) {
    if (t < s) red[t] = fminf(red[t], red[t + s]);
    __syncthreads();
  }
  float mn = red[0];
  __syncthreads();
  red[t] = (t < L_) ? (prof[t] - mn) : -INFINITY;
  __syncthreads();
  for (int s = 128; s > 0; s >>= 1) {
    if (t < s) red[t] = fmaxf(red[t], red[t + s]);
    __syncthreads();
  }
  float mx = red[0];
  __syncthreads();
  red[t] = (t < L_) ? fabsf((prof[t] - mn) / mx - mean[t]) : 0.f;
  __syncthreads();
  for (int s = 128; s > 0; s >>= 1) {
    if (t < s) red[t] += red[t + s];
    __syncthreads();
  }
  if (t == 0) atomicAdd(out, red[0]);
}

extern "C" void kernel_launch(void* const* d_in, const int* in_sizes, int n_in,
                              void* d_out, int out_size, void* d_ws, size_t ws_size,
                              hipStream_t stream) {
  const float* data   = (const float*)d_in[0];  // [128,3,256,256] f32
  const float* mean   = (const float*)d_in[1];  // [182] f32
  const int*   radius = (const int*)d_in[2];    // [256,129] i32
  float* out = (float*)d_out;                   // scalar f32

  float2* inter = (float2*)d_ws;                // [B][WC][H] complex
  size_t inter_bytes = (size_t)B_ * WC_ * H_ * sizeof(float2);
  float* bins   = (float*)((char*)d_ws + inter_bytes);   // [B][L]
  float* counts = bins + (size_t)B_ * L_;                // [L]

  hipMemsetAsync(bins, 0, ((size_t)B_ * L_ + L_) * sizeof(float), stream);
  hipMemsetAsync(out, 0, sizeof(float), stream);

  count_kernel<<<64, 256, 0, stream>>>(radius, counts);
  pass1_kernel<<<B_ * 16, 1024, 0, stream>>>(data, inter);
  pass2_kernel<<<B_ * 33, 256, 0, stream>>>(inter, radius, bins);
  loss_kernel<<<B_, 256, 0, stream>>>(bins, counts, mean, out);
}